// Round 1
// baseline (1055.588 us; speedup 1.0000x reference)
//
#include <hip/hip_runtime.h>
#include <hip/hip_bf16.h>
#include <math.h>

#define N_USERS 100000
#define N_ITEMS 50000
#define N_EDGES 2000000
#define D 64

// ---------------------------------------------------------------------------
// Pass 1: degree counts for both directions
// ---------------------------------------------------------------------------
__global__ void count_kernel(const int* __restrict__ src, const int* __restrict__ dst,
                             int* __restrict__ deg_src, int* __restrict__ deg_dst) {
    int stride = gridDim.x * blockDim.x;
    for (int e = blockIdx.x * blockDim.x + threadIdx.x; e < N_EDGES; e += stride) {
        atomicAdd(&deg_dst[dst[e]], 1);
        atomicAdd(&deg_src[src[e]], 1);
    }
}

// ---------------------------------------------------------------------------
// Single-block exclusive scan (1024 threads, 4 elems/thread, wave-shuffle scan)
// out has n+1 entries; out[n] = total.
// ---------------------------------------------------------------------------
__global__ void scan_excl(const int* __restrict__ in, int* __restrict__ out, int n) {
    const int T = 1024, E = 4;
    __shared__ int wsum[16];
    __shared__ int s_carry;
    if (threadIdx.x == 0) s_carry = 0;
    __syncthreads();

    int lane = threadIdx.x & 63;
    int wid  = threadIdx.x >> 6;

    for (int base = 0; base < n; base += T * E) {
        int idx0 = base + threadIdx.x * E;
        int v[E];
        int tot = 0;
#pragma unroll
        for (int e = 0; e < E; e++) {
            int i = idx0 + e;
            v[e] = (i < n) ? in[i] : 0;
            tot += v[e];
        }
        // inclusive wave scan of per-thread totals
        int incl = tot;
#pragma unroll
        for (int off = 1; off < 64; off <<= 1) {
            int t = __shfl_up(incl, off);
            if (lane >= off) incl += t;
        }
        if (lane == 63) wsum[wid] = incl;
        __syncthreads();
        if (wid == 0 && lane < 16) {
            int t = wsum[lane];
            int sc = t;
#pragma unroll
            for (int off = 1; off < 16; off <<= 1) {
                int u = __shfl_up(sc, off);
                if (lane >= off) sc += u;
            }
            wsum[lane] = sc - t;   // exclusive wave offsets
        }
        __syncthreads();
        int wave_off = wsum[wid];
        int excl = s_carry + wave_off + incl - tot;
#pragma unroll
        for (int e = 0; e < E; e++) {
            int i = idx0 + e;
            if (i < n) out[i] = excl;
            excl += v[e];
        }
        __syncthreads();
        if (threadIdx.x == T - 1) s_carry += wave_off + incl;  // chunk total
        __syncthreads();
    }
    if (threadIdx.x == 0) out[n] = s_carry;
}

// ---------------------------------------------------------------------------
// Pass 2: scatter edge endpoints into CSR lists
// ---------------------------------------------------------------------------
__global__ void fill_kernel(const int* __restrict__ src, const int* __restrict__ dst,
                            int* __restrict__ cur_src, int* __restrict__ cur_dst,
                            int* __restrict__ list_src, int* __restrict__ list_dst) {
    int stride = gridDim.x * blockDim.x;
    for (int e = blockIdx.x * blockDim.x + threadIdx.x; e < N_EDGES; e += stride) {
        int s = src[e], d = dst[e];
        int p = atomicAdd(&cur_dst[d], 1);
        list_dst[p] = s;                 // grouped by dst: stores src ids
        int q = atomicAdd(&cur_src[s], 1);
        list_src[q] = d;                 // grouped by src: stores dst ids
    }
}

// ---------------------------------------------------------------------------
// Global softmax stats over edge_w[N_ITEMS]: stats[0]=max, stats[1]=sum(exp(x-max))
// ---------------------------------------------------------------------------
__global__ void softmax_stats_kernel(const float* __restrict__ w, float* __restrict__ stats) {
    __shared__ float red[16];
    int tid = threadIdx.x, lane = tid & 63, wid = tid >> 6;

    float m = -INFINITY;
    for (int i = tid; i < N_ITEMS; i += 1024) m = fmaxf(m, w[i]);
#pragma unroll
    for (int off = 32; off; off >>= 1) m = fmaxf(m, __shfl_xor(m, off));
    if (lane == 0) red[wid] = m;
    __syncthreads();
    if (tid == 0) {
        float t = red[0];
        for (int k = 1; k < 16; k++) t = fmaxf(t, red[k]);
        red[0] = t;
    }
    __syncthreads();
    m = red[0];
    __syncthreads();

    float s = 0.f;
    for (int i = tid; i < N_ITEMS; i += 1024) s += expf(w[i] - m);
#pragma unroll
    for (int off = 32; off; off >>= 1) s += __shfl_xor(s, off);
    if (lane == 0) red[wid] = s;
    __syncthreads();
    if (tid == 0) {
        float t = 0.f;
        for (int k = 0; k < 16; k++) t += red[k];
        stats[0] = m;
        stats[1] = t;
    }
}

// ---------------------------------------------------------------------------
// Forward: rst[i] = (sum_{(s,i) in E} h_user[s] + 0.5*tanh(pf[i])) * softmax(w)[i] / deg_dst[i]
// One 64-lane group per item; lane = feature index.
// ---------------------------------------------------------------------------
__global__ void forward_kernel(const float* __restrict__ h_user, const float* __restrict__ pf,
                               const float* __restrict__ edge_w,
                               const int* __restrict__ off_dst, const int* __restrict__ list_dst,
                               const float* __restrict__ stats, float* __restrict__ rst) {
    int i = blockIdx.x * 4 + (threadIdx.x >> 6);
    int lane = threadIdx.x & 63;
    if (i >= N_ITEMS) return;
    int beg = off_dst[i], end = off_dst[i + 1];
    float acc = 0.f;
    for (int k = beg; k < end; k++) {
        int s = list_dst[k];
        acc += h_user[(size_t)s * D + lane];
    }
    float m = stats[0], sum = stats[1];
    float sc = expf(edge_w[i] - m) / sum;
    float deg = (float)(end - beg);
    if (deg < 1.f) deg = 1.f;
    float val = (acc + 0.5f * tanhf(pf[(size_t)i * D + lane])) * (sc / deg);
    rst[(size_t)i * D + lane] = val;
}

// ---------------------------------------------------------------------------
// Backward: out[u] = (sum_{(u,d) in E} rst[d]) * deg_src[u]^-1
// ---------------------------------------------------------------------------
__global__ void backward_kernel(const float* __restrict__ rst,
                                const int* __restrict__ off_src, const int* __restrict__ list_src,
                                float* __restrict__ out) {
    int u = blockIdx.x * 4 + (threadIdx.x >> 6);
    int lane = threadIdx.x & 63;
    if (u >= N_USERS) return;
    int beg = off_src[u], end = off_src[u + 1];
    float acc = 0.f;
    for (int k = beg; k < end; k++) {
        int d = list_src[k];
        acc += rst[(size_t)d * D + lane];
    }
    float deg = (float)(end - beg);
    if (deg < 1.f) deg = 1.f;
    out[(size_t)u * D + lane] = acc / deg;
}

// ---------------------------------------------------------------------------
extern "C" void kernel_launch(void* const* d_in, const int* in_sizes, int n_in,
                              void* d_out, int out_size, void* d_ws, size_t ws_size,
                              hipStream_t stream) {
    const float* h_user = (const float*)d_in[0];   // [N_USERS, D]
    const float* pf     = (const float*)d_in[1];   // [N_ITEMS, D]
    const float* edge_w = (const float*)d_in[2];   // [N_ITEMS]
    const int*   src    = (const int*)d_in[3];     // [N_EDGES]
    const int*   dst    = (const int*)d_in[4];     // [N_EDGES]
    float* out = (float*)d_out;                    // [N_USERS, D]

    // workspace carve-up (~31 MB)
    char* p = (char*)d_ws;
    int* deg_dst = (int*)p;  p += sizeof(int) * N_ITEMS;
    int* deg_src = (int*)p;  p += sizeof(int) * N_USERS;
    int* off_dst = (int*)p;  p += sizeof(int) * (N_ITEMS + 1);
    int* off_src = (int*)p;  p += sizeof(int) * (N_USERS + 1);
    int* cur_dst = (int*)p;  p += sizeof(int) * N_ITEMS;
    int* cur_src = (int*)p;  p += sizeof(int) * N_USERS;
    int* list_dst = (int*)p; p += sizeof(int) * N_EDGES;
    int* list_src = (int*)p; p += sizeof(int) * N_EDGES;
    float* rst   = (float*)p; p += sizeof(float) * N_ITEMS * D;
    float* stats = (float*)p; p += 2 * sizeof(float);

    // zero degree counters (deg_dst and deg_src are contiguous)
    hipMemsetAsync(deg_dst, 0, sizeof(int) * (N_ITEMS + N_USERS), stream);

    count_kernel<<<2048, 256, 0, stream>>>(src, dst, deg_src, deg_dst);
    scan_excl<<<1, 1024, 0, stream>>>(deg_dst, off_dst, N_ITEMS);
    scan_excl<<<1, 1024, 0, stream>>>(deg_src, off_src, N_USERS);
    hipMemcpyAsync(cur_dst, off_dst, sizeof(int) * N_ITEMS, hipMemcpyDeviceToDevice, stream);
    hipMemcpyAsync(cur_src, off_src, sizeof(int) * N_USERS, hipMemcpyDeviceToDevice, stream);
    fill_kernel<<<2048, 256, 0, stream>>>(src, dst, cur_src, cur_dst, list_src, list_dst);
    softmax_stats_kernel<<<1, 1024, 0, stream>>>(edge_w, stats);
    forward_kernel<<<(N_ITEMS + 3) / 4, 256, 0, stream>>>(h_user, pf, edge_w, off_dst, list_dst, stats, rst);
    backward_kernel<<<(N_USERS + 3) / 4, 256, 0, stream>>>(rst, off_src, list_src, out);
}